// Round 17
// baseline (595.912 us; speedup 1.0000x reference)
//
#include <hip/hip_runtime.h>
#include <cstdio>
#include <cstdint>

#define BB 16
#define HH 48
#define WW 48
#define DD 384
#define NTOK 2304            // HH*WW
#define EPS 1e-5f
#define SZB 28311552u        // BB*NTOK*DD*2 bytes (one bf16 tensor); xlo = xhi + SZB

typedef __attribute__((ext_vector_type(4))) float f32x4;
typedef __attribute__((ext_vector_type(8))) short bf16x8;
typedef __attribute__((ext_vector_type(4))) short bf16x4;

__device__ __forceinline__ unsigned short f2bf(float f) {
  uint32_t u = __float_as_uint(f);
  uint32_t r = (u + 0x7FFFu + ((u >> 16) & 1u)) >> 16;
  return (unsigned short)r;
}
__device__ __forceinline__ float bf2f(short s) {
  return __uint_as_float(((uint32_t)(unsigned short)s) << 16);
}

typedef __attribute__((address_space(3))) uint32_t lds_u32;
typedef __attribute__((address_space(1))) const uint32_t glob_u32;
__device__ __forceinline__ void gload_lds16(const void* g, void* l) {
  __builtin_amdgcn_global_load_lds((glob_u32*)g, (lds_u32*)l, 16, 0, 0);
}

// ---------------- K1 (fused): x + posenc -> hi/lo bf16 AND vfrag ----------------
__global__ void k_prep(const float* __restrict__ x, const float* __restrict__ Wp,
                       const float* __restrict__ bp, short* __restrict__ xhi,
                       short* __restrict__ xlo, short* __restrict__ vfrag) {
  __shared__ __attribute__((aligned(16))) short tile[32 * 392];
  const int b = blockIdx.y, pt = blockIdx.x, tid = threadIdx.x;
  const int n0 = pt * 32;
  const float* src = x + ((size_t)b * NTOK + n0) * DD;
  short* hdst = xhi + ((size_t)b * NTOK + n0) * DD;
  short* ldst = xlo + ((size_t)b * NTOK + n0) * DD;
#pragma unroll
  for (int c = 0; c < 6; ++c) {
    int u = c * 256 + tid;               // 0..1535
    int r = u / 48, c8 = u % 48;
    int d0 = c8 * 8;
    int n = n0 + r;
    float fh = (float)(n / WW), fw = (float)(n % WW);
    bf16x8 hv, lv;
#pragma unroll
    for (int j = 0; j < 8; ++j) {
      int d = d0 + j;
      float pe = fh * Wp[d] + fw * Wp[DD + d] + bp[d];
      float val = src[(size_t)r * DD + d] + pe;
      unsigned short hb = f2bf(val);
      hv[j] = (short)hb;
      lv[j] = (short)f2bf(val - bf2f((short)hb));
    }
    *(bf16x8*)(&tile[r * 392 + d0]) = hv;
    *(bf16x8*)(hdst + (size_t)r * DD + d0) = hv;
    *(bf16x8*)(ldst + (size_t)r * DD + d0) = lv;
  }
  __syncthreads();
  char* dst = (char*)vfrag + ((size_t)b * 72 + pt) * 24576;
#pragma unroll
  for (int c = 0; c < 6; ++c) {
    int u = c * 256 + tid;
    int db = u >> 6, l = u & 63, l15 = l & 15, lgv = l >> 4;
    bf16x8 vv;
#pragma unroll
    for (int j = 0; j < 8; ++j) {
      int tok = (j < 4) ? (lgv * 4 + j) : (16 + lgv * 4 + (j - 4));
      vv[j] = tile[tok * 392 + db * 16 + l15];
    }
    *(bf16x8*)(dst + (size_t)u * 16) = vv;
  }
}

// ---------------- KW: W1^T, W2^T bf16 ----------------
__global__ void k_wprep(const float* __restrict__ W1, const float* __restrict__ W2,
                        short* __restrict__ w1t, short* __restrict__ w2t) {
  int idx = blockIdx.x * 256 + threadIdx.x;
  int r = idx / DD, c = idx % DD;
  w1t[c * DD + r] = (short)f2bf(W1[idx]);
  w2t[c * DD + r] = (short)f2bf(W2[idx]);
}

// ---------------- K2: flash attention (concurrent KV halves, 1 barrier/pair) ----
// NW=6 (QT=96). Grid 768 = 16 batches x 24 q-tiles x 2 KV-halves = exactly
// 3 full generations of 256 single-CU blocks. Each block runs pairs
// [36h, 36h+36) and writes PARTIAL state (unnormalized O bf16 + per-row m,l).
// FULL double-buffering: K pair-buffers 2x49152 (two 16-key subtiles, each
// hi|lo, XOR-swizzled) + V 2x24576 = 147456 B LDS. One phase per pair:
// issue 12 DMA chunks for p+1 -> 72 QK MFMAs -> softmax -> 24 PV MFMAs ->
// single counted vmcnt(12) + s_barrier. Prefetch never drains in the loop.
__global__ __launch_bounds__(384, 2)
void k_attn(const short* __restrict__ xhi, const short* __restrict__ xlo,
            const short* __restrict__ vfrag, short* __restrict__ o1out,
            short* __restrict__ o2out, float* __restrict__ ml) {
  __shared__ __attribute__((aligned(16))) char lds_all[147456];  // 2xK(49152) + 2xV(24576)
  const int tid = threadIdx.x;
  const int lane = tid & 63, wave = tid >> 6;      // wave 0..5
  const int ln15 = lane & 15, lg = lane >> 4;
  const int bid = blockIdx.x;
  const int xcd = bid & 7, s = bid >> 3;           // s 0..95
  const int bh = (s >= 48) ? 1 : 0;
  const int b = xcd + 8 * bh;                      // batch pinned to XCD
  const int s2 = s - 48 * bh;                      // 0..47
  const int h = s2 / 24;                           // KV half 0/1
  const int qt = s2 % 24;                          // 0..23
  const int q0 = qt * 96;
  const int pair0 = h * 36, pair1 = pair0 + 36;
  const int swz = (ln15 & 7) << 4;

  // K DMA source offsets: 4 chunks x 16B per thread per 24576B subtile.
  uint32_t srcoff[4];
#pragma unroll
  for (int c = 0; c < 4; ++c) {
    int g = c * 6144 + tid * 16;                   // dest byte
    int region = (g >= 12288) ? 1 : 0;             // 0 = hi, 1 = lo
    int rem = g - region * 12288;
    int row = rem / 768;
    int col = rem - row * 768;
    srcoff[c] = (uint32_t)(row * 768 + (col ^ ((row & 7) << 4))) + (region ? SZB : 0u);
  }
  const char* kbp = (const char*)xhi + (size_t)b * NTOK * 768;     // + t*12288 per 16-key tile
  const char* vbp = (const char*)vfrag + (size_t)b * 1769472;      // + p*24576 per pair
  const int dofs = tid * 16;

  // Q hi AND lo fragments resident in registers
  bf16x8 qh[12], ql[12];
  {
    const short* qp = xhi + ((size_t)b * NTOK + q0 + wave * 16 + ln15) * DD + lg * 8;
    const short* qlp = xlo + ((size_t)b * NTOK + q0 + wave * 16 + ln15) * DD + lg * 8;
#pragma unroll
    for (int kf = 0; kf < 12; ++kf) {
      qh[kf] = *(const bf16x8*)(qp + kf * 32);
      ql[kf] = *(const bf16x8*)(qlp + kf * 32);
    }
  }

  f32x4 o[24];
#pragma unroll
  for (int i = 0; i < 24; ++i) o[i] = f32x4{0.f, 0.f, 0.f, 0.f};
  float m1 = -INFINITY, l1 = 0.0f;

  // prologue: K(pair0) both subtiles + V(pair0) into parity-0 buffers; drain.
  {
    const char* kt = kbp + (size_t)(2 * pair0) * 12288;
    const char* vt0 = vbp + (size_t)pair0 * 24576;
#pragma unroll
    for (int c = 0; c < 4; ++c) gload_lds16(kt + srcoff[c], lds_all + c * 6144 + dofs);
#pragma unroll
    for (int c = 0; c < 4; ++c)
      gload_lds16(kt + 12288 + srcoff[c], lds_all + 24576 + c * 6144 + dofs);
#pragma unroll
    for (int c = 0; c < 4; ++c)
      gload_lds16(vt0 + c * 6144 + dofs, lds_all + 98304 + c * 6144 + dofs);
  }
  asm volatile("s_waitcnt vmcnt(0)" ::: "memory");
  __builtin_amdgcn_s_barrier();
  __builtin_amdgcn_sched_barrier(0);

#pragma unroll 1
  for (int p = pair0; p < pair1; ++p) {
    const int par = (p - pair0) & 1;
    char* kc = lds_all + par * 49152;              // current K pair-buffer
    char* vc = lds_all + 98304 + par * 24576;      // current V buffer
    char* kn = lds_all + (par ^ 1) * 49152;        // shadow K
    char* vn = lds_all + 98304 + (par ^ 1) * 24576;// shadow V

    // issue K(p+1) (8 chunks) + V(p+1) (4 chunks) — drained at this pair's barrier
    if (p + 1 < pair1) {
      const char* kt = kbp + (size_t)(2 * (p + 1)) * 12288;
      const char* vt0 = vbp + (size_t)(p + 1) * 24576;
#pragma unroll
      for (int c = 0; c < 4; ++c) gload_lds16(kt + srcoff[c], kn + c * 6144 + dofs);
#pragma unroll
      for (int c = 0; c < 4; ++c)
        gload_lds16(kt + 12288 + srcoff[c], kn + 24576 + c * 6144 + dofs);
#pragma unroll
      for (int c = 0; c < 4; ++c)
        gload_lds16(vt0 + c * 6144 + dofs, vn + c * 6144 + dofs);
    }

    // ---- QK subtile 0 (keys 32p+0..15): 3 chains, LDS+regs only ----
    f32x4 shh = f32x4{0.f, 0.f, 0.f, 0.f}, shl = shh, slh = shh;
    __builtin_amdgcn_s_setprio(1);
#pragma unroll
    for (int kf = 0; kf < 12; ++kf) {
      const int ca = (kf * 64 + lg * 16) ^ swz;
      bf16x8 ah = *(const bf16x8*)(kc + ln15 * 768 + ca);
      bf16x8 al = *(const bf16x8*)(kc + 12288 + ln15 * 768 + ca);
      shh = __builtin_amdgcn_mfma_f32_16x16x32_bf16(ah, qh[kf], shh, 0, 0, 0);
      shl = __builtin_amdgcn_mfma_f32_16x16x32_bf16(ah, ql[kf], shl, 0, 0, 0);
      slh = __builtin_amdgcn_mfma_f32_16x16x32_bf16(al, qh[kf], slh, 0, 0, 0);
    }
    __builtin_amdgcn_s_setprio(0);
    f32x4 sE;
#pragma unroll
    for (int r = 0; r < 4; ++r) sE[r] = shh[r] + shl[r] + slh[r];

    // ---- QK subtile 1 (keys 32p+16..31) ----
    shh = f32x4{0.f, 0.f, 0.f, 0.f}; shl = shh; slh = shh;
    __builtin_amdgcn_s_setprio(1);
#pragma unroll
    for (int kf = 0; kf < 12; ++kf) {
      const int ca = (kf * 64 + lg * 16) ^ swz;
      bf16x8 ah = *(const bf16x8*)(kc + 24576 + ln15 * 768 + ca);
      bf16x8 al = *(const bf16x8*)(kc + 36864 + ln15 * 768 + ca);
      shh = __builtin_amdgcn_mfma_f32_16x16x32_bf16(ah, qh[kf], shh, 0, 0, 0);
      shl = __builtin_amdgcn_mfma_f32_16x16x32_bf16(ah, ql[kf], shl, 0, 0, 0);
      slh = __builtin_amdgcn_mfma_f32_16x16x32_bf16(al, qh[kf], slh, 0, 0, 0);
    }
    __builtin_amdgcn_s_setprio(0);
    f32x4 sO;
#pragma unroll
    for (int r = 0; r < 4; ++r) sO[r] = shh[r] + shl[r] + slh[r];

    // ---- softmax over 32 keys (lane owns q=ln15; keys lg*4+r / 16+lg*4+r) ----
    float tmax = -INFINITY;
#pragma unroll
    for (int r = 0; r < 4; ++r) tmax = fmaxf(tmax, fmaxf(sE[r], sO[r]));
    tmax = fmaxf(tmax, __shfl_xor(tmax, 16));
    tmax = fmaxf(tmax, __shfl_xor(tmax, 32));
    if (__any(tmax - m1 > 8.f)) {                  // defer-max
      float mn = fmaxf(m1, tmax);
      float al_ = __expf(m1 - mn);
      float alr[4];
#pragma unroll
      for (int r = 0; r < 4; ++r) alr[r] = __shfl(al_, lg * 4 + r);
#pragma unroll
      for (int ob = 0; ob < 24; ++ob)
#pragma unroll
        for (int r = 0; r < 4; ++r) o[ob][r] *= alr[r];
      l1 *= al_;
      m1 = mn;
    }
    float rs = 0.0f;
    bf16x8 p8;
#pragma unroll
    for (int r = 0; r < 4; ++r) {
      float pe = __expf(sE[r] - m1);
      float po = __expf(sO[r] - m1);
      rs += pe + po;
      p8[r] = (short)f2bf(pe);
      p8[r + 4] = (short)f2bf(po);
    }
    rs += __shfl_xor(rs, 16);
    rs += __shfl_xor(rs, 32);
    l1 += rs;

    // ---- PV: one k=32 MFMA per 16-d block; V fragments from LDS (vc) ----
    const char* vt = vc + lane * 16;
    __builtin_amdgcn_s_setprio(1);
#pragma unroll
    for (int g = 0; g < 4; ++g) {
#pragma unroll
      for (int j = 0; j < 6; ++j) {
        bf16x8 vv = *(const bf16x8*)(vt + (g * 6 + j) * 1024);
        o[g * 6 + j] = __builtin_amdgcn_mfma_f32_16x16x32_bf16(p8, vv, o[g * 6 + j], 0, 0, 0);
      }
    }
    __builtin_amdgcn_s_setprio(0);

    // single barrier: K(p+1)/V(p+1) (12 loads) stay in flight; older loads done.
    if (p + 1 < pair1) {
      asm volatile("s_waitcnt vmcnt(12)" ::: "memory");
    } else {
      asm volatile("s_waitcnt vmcnt(0)" ::: "memory");
    }
    __builtin_amdgcn_s_barrier();
    __builtin_amdgcn_sched_barrier(0);
  }

  // epilogue: store PARTIAL state (unnormalized O bf16 + per-row m,l)
  short* ob_ = (h == 0 ? o1out : o2out) + ((size_t)b * NTOK + q0 + wave * 16) * DD;
#pragma unroll
  for (int db = 0; db < 24; ++db)
#pragma unroll
    for (int r = 0; r < 4; ++r)
      ob_[(size_t)(lg * 4 + r) * DD + db * 16 + ln15] = (short)f2bf(o[db][r]);
  if (lg == 0) {
    float2 mv;
    mv.x = m1;
    mv.y = l1;
    ((float2*)ml)[(size_t)h * (BB * NTOK) + (size_t)b * NTOK + q0 + wave * 16 + ln15] = mv;
  }
}

// ---------------- KC: combine the two KV-half partials -> normalized O (bf16) ----
__global__ void k_comb(const short* __restrict__ o1, const short* __restrict__ o2,
                       const float* __restrict__ ml, short* __restrict__ aout) {
  size_t i8 = ((size_t)blockIdx.x * 256 + threadIdx.x) * 8;
  size_t row = i8 / DD;
  float2 s1 = ((const float2*)ml)[row];
  float2 s2 = ((const float2*)ml)[(size_t)BB * NTOK + row];
  float m = fmaxf(s1.x, s2.x);
  float a1 = __expf(s1.x - m), a2 = __expf(s2.x - m);
  float inv = 1.0f / (a1 * s1.y + a2 * s2.y);
  bf16x8 v1 = *(const bf16x8*)(o1 + i8);
  bf16x8 v2 = *(const bf16x8*)(o2 + i8);
  bf16x8 w;
#pragma unroll
  for (int j = 0; j < 8; ++j)
    w[j] = (short)f2bf((a1 * bf2f(v1[j]) + a2 * bf2f(v2[j])) * inv);
  *(bf16x8*)(aout + i8) = w;
}

// ---------------- K3: MLP + residual + LN stats; y stored bf16 in-place ----------------
__global__ __launch_bounds__(128, 3)
void k_mlp(const short* __restrict__ aout, const short* __restrict__ w1t,
           const short* __restrict__ w2t, const float* __restrict__ b1,
           const float* __restrict__ b2, const short* __restrict__ xhi,
           const short* __restrict__ xlo, short* __restrict__ ybf,
           float* __restrict__ stats) {
  __shared__ __attribute__((aligned(16))) short hid[2 * 16 * 392];
  __shared__ float redS[2], redQ[2];
  const int tid = threadIdx.x, lane = tid & 63, wave = tid >> 6;
  const int ln15 = lane & 15, lg = lane >> 4;
  const int row0 = blockIdx.x * 32;
  const int bb = row0 / NTOK;

  bf16x8 a[12];
  {
    const short* ap = aout + (size_t)(row0 + wave * 16 + ln15) * DD + lg * 8;
#pragma unroll
    for (int kf = 0; kf < 12; ++kf) a[kf] = *(const bf16x8*)(ap + kf * 32);
  }
  short* hw = &hid[wave * 16 * 392];
#pragma unroll 1
  for (int cb = 0; cb < 24; ++cb) {
    f32x4 acc = f32x4{0.f, 0.f, 0.f, 0.f};
#pragma unroll
    for (int kf = 0; kf < 12; ++kf) {
      bf16x8 wf = *(const bf16x8*)(w1t + (size_t)(cb * 16 + ln15) * DD + kf * 32 + lg * 8);
      acc = __builtin_amdgcn_mfma_f32_16x16x32_bf16(a[kf], wf, acc, 0, 0, 0);
    }
    float bias = b1[cb * 16 + ln15];
#pragma unroll
    for (int r = 0; r < 4; ++r) {
      float v = fmaxf(acc[r] + bias, 0.0f);
      hw[(lg * 4 + r) * 392 + cb * 16 + ln15] = (short)f2bf(v);
    }
  }
  __syncthreads();
  bf16x8 h[12];
#pragma unroll
  for (int kf = 0; kf < 12; ++kf)
    h[kf] = *(const bf16x8*)(&hw[ln15 * 392 + kf * 32 + lg * 8]);
  float ts = 0.f, tq = 0.f;
#pragma unroll 1
  for (int cb = 0; cb < 24; ++cb) {
    f32x4 acc = f32x4{0.f, 0.f, 0.f, 0.f};
#pragma unroll
    for (int kf = 0; kf < 12; ++kf) {
      bf16x8 wf = *(const bf16x8*)(w2t + (size_t)(cb * 16 + ln15) * DD + kf * 32 + lg * 8);
      acc = __builtin_amdgcn_mfma_f32_16x16x32_bf16(h[kf], wf, acc, 0, 0, 0);
    }
    int col = cb * 16 + ln15;
    float bias = b2[col];
#pragma unroll
    for (int r = 0; r < 4; ++r) {
      size_t row = (size_t)row0 + wave * 16 + lg * 4 + r;
      size_t idx = row * DD + col;
      float xv = bf2f(xhi[idx]) + bf2f(xlo[idx]);
      float y = acc[r] + bias + xv;
      ybf[idx] = (short)f2bf(y);     // bf16 y (in-place over aout — rows owned by this block)
      ts += y;
      tq += y * y;
    }
  }
#pragma unroll
  for (int off = 32; off; off >>= 1) {
    ts += __shfl_xor(ts, off);
    tq += __shfl_xor(tq, off);
  }
  if (lane == 0) { redS[wave] = ts; redQ[wave] = tq; }
  __syncthreads();
  if (tid == 0) {
    atomicAdd(&stats[bb], redS[0] + redS[1]);
    atomicAdd(&stats[16 + bb], redQ[0] + redQ[1]);
  }
}

// ---------------- K4: LayerNorm (bf16 y -> f32 out) ----------------
__global__ void k_ln(const short* __restrict__ ybf, float* __restrict__ out,
                     const float* __restrict__ stats) {
  size_t i8 = ((size_t)blockIdx.x * 256 + threadIdx.x) * 8;
  int b = (int)(i8 / ((size_t)NTOK * DD));
  const float cnt = (float)(NTOK * DD);
  float mean = stats[b] / cnt;
  float var = stats[16 + b] / cnt - mean * mean;
  float inv = rsqrtf(var + EPS);
  bf16x8 v = *(const bf16x8*)(ybf + i8);
  f32x4 o0, o1;
#pragma unroll
  for (int j = 0; j < 4; ++j) {
    o0[j] = (bf2f(v[j]) - mean) * inv;
    o1[j] = (bf2f(v[j + 4]) - mean) * inv;
  }
  *(f32x4*)(out + i8) = o0;
  *(f32x4*)(out + i8 + 4) = o1;
}

// ---------------- launcher ----------------
extern "C" void kernel_launch(void* const* d_in, const int* in_sizes, int n_in,
                              void* d_out, int out_size, void* d_ws, size_t ws_size,
                              hipStream_t stream) {
  const float* x  = (const float*)d_in[0];
  const float* Wp = (const float*)d_in[1];
  const float* bp = (const float*)d_in[2];
  const float* W1 = (const float*)d_in[3];
  const float* b1 = (const float*)d_in[4];
  const float* W2 = (const float*)d_in[5];
  const float* b2 = (const float*)d_in[6];
  float* out = (float*)d_out;

  const size_t SZ = (size_t)SZB;   // 28,311,552 bytes
  char* ws = (char*)d_ws;
  short* xhi   = (short*)ws;
  short* xlo   = (short*)(ws + SZ);      // MUST stay at xhi+SZB (srcoff relies on it)
  short* vfrag = (short*)(ws + 2 * SZ);
  short* aout  = (short*)(ws + 3 * SZ);  // half-0 partial O / combined O / bf16 y
  short* o2    = (short*)d_out;          // half-1 partial O (d_out as scratch; consumed
                                         // by k_comb before k_ln overwrites d_out)
  short* w1t   = (short*)(ws + 4 * SZ);
  short* w2t   = (short*)(ws + 4 * SZ + 294912);
  float* stats = (float*)(ws + 4 * SZ + 2 * 294912);
  float* ml    = (float*)(ws + 4 * SZ + 2 * 294912 + 256);   // 2 halves x (m,l)/row: 589824 B
  const size_t need = 4 * SZ + 2 * 294912 + 256 + 589824 + 128;
  if (ws_size < need) {
    fprintf(stderr, "kernel_launch: ws_size %zu < needed %zu\n", ws_size, need);
  }

  k_prep<<<dim3(72, 16), 256, 0, stream>>>(x, Wp, bp, xhi, xlo, vfrag);
  k_wprep<<<576, 256, 0, stream>>>(W1, W2, w1t, w2t);
  k_attn<<<768, 384, 0, stream>>>(xhi, xlo, vfrag, aout, o2, ml);
  k_comb<<<6912, 256, 0, stream>>>(aout, o2, ml, aout);
  hipMemsetAsync(stats, 0, 32 * sizeof(float), stream);
  k_mlp<<<1152, 128, 0, stream>>>(aout, w1t, w2t, b1, b2, xhi, xlo, aout, stats);
  k_ln<<<6912, 256, 0, stream>>>(aout, out, stats);
}

// Round 18
// 568.356 us; speedup vs baseline: 1.0485x; 1.0485x over previous
//
#include <hip/hip_runtime.h>
#include <cstdio>
#include <cstdint>

#define BB 16
#define HH 48
#define WW 48
#define DD 384
#define NTOK 2304            // HH*WW
#define EPS 1e-5f
#define SZB 28311552u        // BB*NTOK*DD*2 bytes (one bf16 tensor); xlo = xhi + SZB

typedef __attribute__((ext_vector_type(4))) float f32x4;
typedef __attribute__((ext_vector_type(8))) short bf16x8;
typedef __attribute__((ext_vector_type(4))) short bf16x4;

__device__ __forceinline__ unsigned short f2bf(float f) {
  uint32_t u = __float_as_uint(f);
  uint32_t r = (u + 0x7FFFu + ((u >> 16) & 1u)) >> 16;
  return (unsigned short)r;
}
__device__ __forceinline__ float bf2f(short s) {
  return __uint_as_float(((uint32_t)(unsigned short)s) << 16);
}

typedef __attribute__((address_space(3))) uint32_t lds_u32;
typedef __attribute__((address_space(1))) const uint32_t glob_u32;
__device__ __forceinline__ void gload_lds16(const void* g, void* l) {
  __builtin_amdgcn_global_load_lds((glob_u32*)g, (lds_u32*)l, 16, 0, 0);
}

// ---------------- K1 (fused): x + posenc -> hi/lo bf16 AND vfrag ----------------
__global__ void k_prep(const float* __restrict__ x, const float* __restrict__ Wp,
                       const float* __restrict__ bp, short* __restrict__ xhi,
                       short* __restrict__ xlo, short* __restrict__ vfrag) {
  __shared__ __attribute__((aligned(16))) short tile[32 * 392];
  const int b = blockIdx.y, pt = blockIdx.x, tid = threadIdx.x;
  const int n0 = pt * 32;
  const float* src = x + ((size_t)b * NTOK + n0) * DD;
  short* hdst = xhi + ((size_t)b * NTOK + n0) * DD;
  short* ldst = xlo + ((size_t)b * NTOK + n0) * DD;
#pragma unroll
  for (int c = 0; c < 6; ++c) {
    int u = c * 256 + tid;               // 0..1535
    int r = u / 48, c8 = u % 48;
    int d0 = c8 * 8;
    int n = n0 + r;
    float fh = (float)(n / WW), fw = (float)(n % WW);
    bf16x8 hv, lv;
#pragma unroll
    for (int j = 0; j < 8; ++j) {
      int d = d0 + j;
      float pe = fh * Wp[d] + fw * Wp[DD + d] + bp[d];
      float val = src[(size_t)r * DD + d] + pe;
      unsigned short hb = f2bf(val);
      hv[j] = (short)hb;
      lv[j] = (short)f2bf(val - bf2f((short)hb));
    }
    *(bf16x8*)(&tile[r * 392 + d0]) = hv;
    *(bf16x8*)(hdst + (size_t)r * DD + d0) = hv;
    *(bf16x8*)(ldst + (size_t)r * DD + d0) = lv;
  }
  __syncthreads();
  char* dst = (char*)vfrag + ((size_t)b * 72 + pt) * 24576;
#pragma unroll
  for (int c = 0; c < 6; ++c) {
    int u = c * 256 + tid;
    int db = u >> 6, l = u & 63, l15 = l & 15, lgv = l >> 4;
    bf16x8 vv;
#pragma unroll
    for (int j = 0; j < 8; ++j) {
      int tok = (j < 4) ? (lgv * 4 + j) : (16 + lgv * 4 + (j - 4));
      vv[j] = tile[tok * 392 + db * 16 + l15];
    }
    *(bf16x8*)(dst + (size_t)u * 16) = vv;
  }
}

// ---------------- KW: W1^T, W2^T bf16 ----------------
__global__ void k_wprep(const float* __restrict__ W1, const float* __restrict__ W2,
                        short* __restrict__ w1t, short* __restrict__ w2t) {
  int idx = blockIdx.x * 256 + threadIdx.x;
  int r = idx / DD, c = idx % DD;
  w1t[c * DD + r] = (short)f2bf(W1[idx]);
  w2t[c * DD + r] = (short)f2bf(W2[idx]);
}

// ---------------- K2: flash attention (concurrent KV halves; r16 pipeline) ----
// NW=6 (QT=96). Grid 768 = 16 batches x 24 q-tiles x 2 KV-halves = exactly
// 3 full generations of 256 single-CU blocks. Each block runs pairs
// [36h, 36h+36) and writes PARTIAL state (unnormalized O bf16 + per-row m,l);
// the combine happens inside k_mlp. Batch pinned per XCD.
// K in 3 rotating 24KB LDS buffers (16 rows hi+lo, XOR-swizzled), V pair-tiles
// double-buffered, global_load_lds DMA with counted vmcnt + raw s_barrier
// (prefetch never drains inside the loop).
__global__ __launch_bounds__(384, 2)
void k_attn(const short* __restrict__ xhi, const short* __restrict__ xlo,
            const short* __restrict__ vfrag, short* __restrict__ o1out,
            short* __restrict__ o2out, float* __restrict__ ml) {
  __shared__ __attribute__((aligned(16))) char lds_all[122880];  // 3xK + 2xV
  const int tid = threadIdx.x;
  const int lane = tid & 63, wave = tid >> 6;      // wave 0..5
  const int ln15 = lane & 15, lg = lane >> 4;
  const int bid = blockIdx.x;
  const int xcd = bid & 7, s = bid >> 3;           // s 0..95
  const int bh = (s >= 48) ? 1 : 0;
  const int b = xcd + 8 * bh;                      // batch pinned to XCD
  const int s2 = s - 48 * bh;                      // 0..47
  const int h = s2 / 24;                           // KV half 0/1
  const int qt = s2 % 24;                          // 0..23
  const int q0 = qt * 96;
  const int pair0 = h * 36, pair1 = pair0 + 36;
  const int swz = (ln15 & 7) << 4;

  // K DMA source offsets: 4 chunks x 16B per thread per 24576B tile.
  uint32_t srcoff[4];
#pragma unroll
  for (int c = 0; c < 4; ++c) {
    int g = c * 6144 + tid * 16;                   // dest byte
    int region = (g >= 12288) ? 1 : 0;             // 0 = hi, 1 = lo
    int rem = g - region * 12288;
    int row = rem / 768;
    int col = rem - row * 768;
    srcoff[c] = (uint32_t)(row * 768 + (col ^ ((row & 7) << 4))) + (region ? SZB : 0u);
  }
  const char* kbp = (const char*)xhi + (size_t)b * NTOK * 768;     // + t*12288 per tile
  const char* vbp = (const char*)vfrag + (size_t)b * 1769472;      // + p*24576 per pair
  const int dofs = tid * 16;

  // Q hi AND lo fragments resident in registers
  bf16x8 qh[12], ql[12];
  {
    const short* qp = xhi + ((size_t)b * NTOK + q0 + wave * 16 + ln15) * DD + lg * 8;
    const short* qlp = xlo + ((size_t)b * NTOK + q0 + wave * 16 + ln15) * DD + lg * 8;
#pragma unroll
    for (int kf = 0; kf < 12; ++kf) {
      qh[kf] = *(const bf16x8*)(qp + kf * 32);
      ql[kf] = *(const bf16x8*)(qlp + kf * 32);
    }
  }

  f32x4 o[24];
#pragma unroll
  for (int i = 0; i < 24; ++i) o[i] = f32x4{0.f, 0.f, 0.f, 0.f};
  float m1 = -INFINITY, l1 = 0.0f;

  char* bA = lds_all;            // K tile 2p
  char* bB = lds_all + 24576;    // K tile 2p+1
  char* bC = lds_all + 49152;    // DMA target for K tile 2p+2
  char* vA = lds_all + 73728;    // V pair p
  char* vB = lds_all + 98304;    // DMA target for V pair p+1

  // prologue: K(2*pair0)->bA, K(2*pair0+1)->bB, V(pair0)->vA
  {
    const char* kt = kbp + (size_t)(2 * pair0) * 12288;
    const char* vt0 = vbp + (size_t)pair0 * 24576;
#pragma unroll
    for (int c = 0; c < 4; ++c) gload_lds16(kt + srcoff[c], bA + c * 6144 + dofs);
#pragma unroll
    for (int c = 0; c < 4; ++c) gload_lds16(kt + 12288 + srcoff[c], bB + c * 6144 + dofs);
#pragma unroll
    for (int c = 0; c < 4; ++c) gload_lds16(vt0 + c * 6144 + dofs, vA + c * 6144 + dofs);
  }
  asm volatile("s_waitcnt vmcnt(8)" ::: "memory");   // K(2p0) done; K(2p0+1),V(p0) in flight
  __builtin_amdgcn_s_barrier();
  __builtin_amdgcn_sched_barrier(0);

#pragma unroll 1
  for (int p = pair0; p < pair1; ++p) {
    // ======== even phase: K tile 2p in bA ========
    if (2 * p + 2 < 2 * pair1) {                   // issue K(2p+2) -> bC
      const char* kn = kbp + (size_t)(2 * p + 2) * 12288;
#pragma unroll
      for (int c = 0; c < 4; ++c) gload_lds16(kn + srcoff[c], bC + c * 6144 + dofs);
    }
    f32x4 shh = f32x4{0.f, 0.f, 0.f, 0.f}, shl = shh, slh = shh;
    __builtin_amdgcn_s_setprio(1);
#pragma unroll
    for (int kf = 0; kf < 12; ++kf) {
      const int ca = (kf * 64 + lg * 16) ^ swz;
      bf16x8 ah = *(const bf16x8*)(bA + ln15 * 768 + ca);
      bf16x8 al = *(const bf16x8*)(bA + 12288 + ln15 * 768 + ca);
      shh = __builtin_amdgcn_mfma_f32_16x16x32_bf16(ah, qh[kf], shh, 0, 0, 0);
      shl = __builtin_amdgcn_mfma_f32_16x16x32_bf16(ah, ql[kf], shl, 0, 0, 0);
      slh = __builtin_amdgcn_mfma_f32_16x16x32_bf16(al, qh[kf], slh, 0, 0, 0);
    }
    __builtin_amdgcn_s_setprio(0);
    f32x4 sE;
#pragma unroll
    for (int r = 0; r < 4; ++r) sE[r] = shh[r] + shl[r] + slh[r];

    // barrier E: K(2p+1) and V(p) must be done; K(2p+2) stays in flight.
    if (p + 1 < pair1) {
      asm volatile("s_waitcnt vmcnt(4)" ::: "memory");
    } else {
      asm volatile("s_waitcnt vmcnt(0)" ::: "memory");   // last pair: drain V(p)
    }
    __builtin_amdgcn_s_barrier();
    __builtin_amdgcn_sched_barrier(0);

    // ======== odd phase: K tile 2p+1 in bB; PV uses V(p) in vA ========
    if (2 * p + 3 < 2 * pair1) {                   // issue K(2p+3) -> bA
      const char* kn = kbp + (size_t)(2 * p + 3) * 12288;
#pragma unroll
      for (int c = 0; c < 4; ++c) gload_lds16(kn + srcoff[c], bA + c * 6144 + dofs);
    }
    if (p + 1 < pair1) {                           // issue V(p+1) -> vB
      const char* vn = vbp + (size_t)(p + 1) * 24576;
#pragma unroll
      for (int c = 0; c < 4; ++c) gload_lds16(vn + c * 6144 + dofs, vB + c * 6144 + dofs);
    }
    shh = f32x4{0.f, 0.f, 0.f, 0.f}; shl = shh; slh = shh;
    __builtin_amdgcn_s_setprio(1);
#pragma unroll
    for (int kf = 0; kf < 12; ++kf) {
      const int ca = (kf * 64 + lg * 16) ^ swz;
      bf16x8 ah = *(const bf16x8*)(bB + ln15 * 768 + ca);
      bf16x8 al = *(const bf16x8*)(bB + 12288 + ln15 * 768 + ca);
      shh = __builtin_amdgcn_mfma_f32_16x16x32_bf16(ah, qh[kf], shh, 0, 0, 0);
      shl = __builtin_amdgcn_mfma_f32_16x16x32_bf16(ah, ql[kf], shl, 0, 0, 0);
      slh = __builtin_amdgcn_mfma_f32_16x16x32_bf16(al, qh[kf], slh, 0, 0, 0);
    }
    __builtin_amdgcn_s_setprio(0);
    f32x4 sO;
#pragma unroll
    for (int r = 0; r < 4; ++r) sO[r] = shh[r] + shl[r] + slh[r];

    // ---- softmax over 32 keys (lane owns q=ln15; keys lg*4+r / 16+lg*4+r) ----
    float tmax = -INFINITY;
#pragma unroll
    for (int r = 0; r < 4; ++r) tmax = fmaxf(tmax, fmaxf(sE[r], sO[r]));
    tmax = fmaxf(tmax, __shfl_xor(tmax, 16));
    tmax = fmaxf(tmax, __shfl_xor(tmax, 32));
    if (__any(tmax - m1 > 8.f)) {                  // defer-max
      float mn = fmaxf(m1, tmax);
      float al_ = __expf(m1 - mn);
      float alr[4];
#pragma unroll
      for (int r = 0; r < 4; ++r) alr[r] = __shfl(al_, lg * 4 + r);
#pragma unroll
      for (int ob = 0; ob < 24; ++ob)
#pragma unroll
        for (int r = 0; r < 4; ++r) o[ob][r] *= alr[r];
      l1 *= al_;
      m1 = mn;
    }
    float rs = 0.0f;
    bf16x8 p8;
#pragma unroll
    for (int r = 0; r < 4; ++r) {
      float pe = __expf(sE[r] - m1);
      float po = __expf(sO[r] - m1);
      rs += pe + po;
      p8[r] = (short)f2bf(pe);
      p8[r + 4] = (short)f2bf(po);
    }
    rs += __shfl_xor(rs, 16);
    rs += __shfl_xor(rs, 32);
    l1 += rs;

    // ---- PV: one k=32 MFMA per 16-d block; V fragments from LDS (vA) ----
    const char* vt = vA + lane * 16;
    __builtin_amdgcn_s_setprio(1);
#pragma unroll
    for (int g = 0; g < 4; ++g) {
#pragma unroll
      for (int j = 0; j < 6; ++j) {
        bf16x8 vv = *(const bf16x8*)(vt + (g * 6 + j) * 1024);
        o[g * 6 + j] = __builtin_amdgcn_mfma_f32_16x16x32_bf16(p8, vv, o[g * 6 + j], 0, 0, 0);
      }
    }
    __builtin_amdgcn_s_setprio(0);

    // barrier O: K(2p+2) must be done; K(2p+3) + V(p+1) stay in flight.
    asm volatile("s_waitcnt vmcnt(8)" ::: "memory");
    __builtin_amdgcn_s_barrier();
    __builtin_amdgcn_sched_barrier(0);

    // rotate K buffers: bA' = bC (2p+2), bB' = bA (2p+3), bC' = bB (free)
    char* t0 = bA;
    char* t1 = bB;
    bA = bC; bB = t0; bC = t1;
    // swap V buffers: vA' = V(p+1)
    char* tv = vA; vA = vB; vB = tv;
  }

  // epilogue: store PARTIAL state (unnormalized O bf16 + per-row m,l)
  short* ob_ = (h == 0 ? o1out : o2out) + ((size_t)b * NTOK + q0 + wave * 16) * DD;
#pragma unroll
  for (int db = 0; db < 24; ++db)
#pragma unroll
    for (int r = 0; r < 4; ++r)
      ob_[(size_t)(lg * 4 + r) * DD + db * 16 + ln15] = (short)f2bf(o[db][r]);
  if (lg == 0) {
    float2 mv;
    mv.x = m1;
    mv.y = l1;
    ((float2*)ml)[(size_t)h * (BB * NTOK) + (size_t)b * NTOK + q0 + wave * 16 + ln15] = mv;
  }
}

// ---------------- K3: combine halves + MLP + residual + LN stats; y bf16 in-place ----
__global__ __launch_bounds__(128, 3)
void k_mlp(const short* __restrict__ o1, const short* __restrict__ o2,
           const float* __restrict__ ml, const short* __restrict__ w1t,
           const short* __restrict__ w2t, const float* __restrict__ b1,
           const float* __restrict__ b2, const short* __restrict__ xhi,
           const short* __restrict__ xlo, short* __restrict__ ybf,
           float* __restrict__ stats) {
  __shared__ __attribute__((aligned(16))) short hid[2 * 16 * 392];
  __shared__ float redS[2], redQ[2];
  const int tid = threadIdx.x, lane = tid & 63, wave = tid >> 6;
  const int ln15 = lane & 15, lg = lane >> 4;
  const int row0 = blockIdx.x * 32;
  const int bb = row0 / NTOK;

  // combine KV-half partials for this lane's row while loading a[] fragments
  bf16x8 a[12];
  {
    const size_t row = (size_t)row0 + wave * 16 + ln15;
    float2 s1 = ((const float2*)ml)[row];
    float2 s2 = ((const float2*)ml)[(size_t)BB * NTOK + row];
    float m = fmaxf(s1.x, s2.x);
    float a1 = __expf(s1.x - m), a2 = __expf(s2.x - m);
    float inv = 1.0f / (a1 * s1.y + a2 * s2.y);
    a1 *= inv;
    a2 *= inv;
    const short* p1 = o1 + row * DD + lg * 8;
    const short* p2 = o2 + row * DD + lg * 8;
#pragma unroll
    for (int kf = 0; kf < 12; ++kf) {
      bf16x8 v1 = *(const bf16x8*)(p1 + kf * 32);
      bf16x8 v2 = *(const bf16x8*)(p2 + kf * 32);
      bf16x8 cv;
#pragma unroll
      for (int j = 0; j < 8; ++j)
        cv[j] = (short)f2bf(a1 * bf2f(v1[j]) + a2 * bf2f(v2[j]));
      a[kf] = cv;
    }
  }
  short* hw = &hid[wave * 16 * 392];
#pragma unroll 1
  for (int cb = 0; cb < 24; ++cb) {
    f32x4 acc = f32x4{0.f, 0.f, 0.f, 0.f};
#pragma unroll
    for (int kf = 0; kf < 12; ++kf) {
      bf16x8 wf = *(const bf16x8*)(w1t + (size_t)(cb * 16 + ln15) * DD + kf * 32 + lg * 8);
      acc = __builtin_amdgcn_mfma_f32_16x16x32_bf16(a[kf], wf, acc, 0, 0, 0);
    }
    float bias = b1[cb * 16 + ln15];
#pragma unroll
    for (int r = 0; r < 4; ++r) {
      float v = fmaxf(acc[r] + bias, 0.0f);
      hw[(lg * 4 + r) * 392 + cb * 16 + ln15] = (short)f2bf(v);
    }
  }
  __syncthreads();
  bf16x8 h[12];
#pragma unroll
  for (int kf = 0; kf < 12; ++kf)
    h[kf] = *(const bf16x8*)(&hw[ln15 * 392 + kf * 32 + lg * 8]);
  float ts = 0.f, tq = 0.f;
#pragma unroll 1
  for (int cb = 0; cb < 24; ++cb) {
    f32x4 acc = f32x4{0.f, 0.f, 0.f, 0.f};
#pragma unroll
    for (int kf = 0; kf < 12; ++kf) {
      bf16x8 wf = *(const bf16x8*)(w2t + (size_t)(cb * 16 + ln15) * DD + kf * 32 + lg * 8);
      acc = __builtin_amdgcn_mfma_f32_16x16x32_bf16(h[kf], wf, acc, 0, 0, 0);
    }
    int col = cb * 16 + ln15;
    float bias = b2[col];
#pragma unroll
    for (int r = 0; r < 4; ++r) {
      size_t row = (size_t)row0 + wave * 16 + lg * 4 + r;
      size_t idx = row * DD + col;
      float xv = bf2f(xhi[idx]) + bf2f(xlo[idx]);
      float y = acc[r] + bias + xv;
      ybf[idx] = (short)f2bf(y);     // bf16 y (in-place over o1 — rows owned by this block)
      ts += y;
      tq += y * y;
    }
  }
#pragma unroll
  for (int off = 32; off; off >>= 1) {
    ts += __shfl_xor(ts, off);
    tq += __shfl_xor(tq, off);
  }
  if (lane == 0) { redS[wave] = ts; redQ[wave] = tq; }
  __syncthreads();
  if (tid == 0) {
    atomicAdd(&stats[bb], redS[0] + redS[1]);
    atomicAdd(&stats[16 + bb], redQ[0] + redQ[1]);
  }
}

// ---------------- K4: LayerNorm (bf16 y -> f32 out) ----------------
__global__ void k_ln(const short* __restrict__ ybf, float* __restrict__ out,
                     const float* __restrict__ stats) {
  size_t i8 = ((size_t)blockIdx.x * 256 + threadIdx.x) * 8;
  int b = (int)(i8 / ((size_t)NTOK * DD));
  const float cnt = (float)(NTOK * DD);
  float mean = stats[b] / cnt;
  float var = stats[16 + b] / cnt - mean * mean;
  float inv = rsqrtf(var + EPS);
  bf16x8 v = *(const bf16x8*)(ybf + i8);
  f32x4 o0, o1;
#pragma unroll
  for (int j = 0; j < 4; ++j) {
    o0[j] = (bf2f(v[j]) - mean) * inv;
    o1[j] = (bf2f(v[j + 4]) - mean) * inv;
  }
  *(f32x4*)(out + i8) = o0;
  *(f32x4*)(out + i8 + 4) = o1;
}

// ---------------- launcher ----------------
extern "C" void kernel_launch(void* const* d_in, const int* in_sizes, int n_in,
                              void* d_out, int out_size, void* d_ws, size_t ws_size,
                              hipStream_t stream) {
  const float* x  = (const float*)d_in[0];
  const float* Wp = (const float*)d_in[1];
  const float* bp = (const float*)d_in[2];
  const float* W1 = (const float*)d_in[3];
  const float* b1 = (const float*)d_in[4];
  const float* W2 = (const float*)d_in[5];
  const float* b2 = (const float*)d_in[6];
  float* out = (float*)d_out;

  const size_t SZ = (size_t)SZB;   // 28,311,552 bytes
  char* ws = (char*)d_ws;
  short* xhi   = (short*)ws;
  short* xlo   = (short*)(ws + SZ);      // MUST stay at xhi+SZB (srcoff relies on it)
  short* vfrag = (short*)(ws + 2 * SZ);
  short* aout  = (short*)(ws + 3 * SZ);  // half-0 partial O; then bf16 y (in-place)
  short* o2    = (short*)d_out;          // half-1 partial O (d_out as scratch; consumed
                                         // by k_mlp before k_ln overwrites d_out)
  short* w1t   = (short*)(ws + 4 * SZ);
  short* w2t   = (short*)(ws + 4 * SZ + 294912);
  float* stats = (float*)(ws + 4 * SZ + 2 * 294912);
  float* ml    = (float*)(ws + 4 * SZ + 2 * 294912 + 256);   // 2 halves x (m,l)/row: 589824 B
  const size_t need = 4 * SZ + 2 * 294912 + 256 + 589824 + 128;
  if (ws_size < need) {
    fprintf(stderr, "kernel_launch: ws_size %zu < needed %zu\n", ws_size, need);
  }

  k_prep<<<dim3(72, 16), 256, 0, stream>>>(x, Wp, bp, xhi, xlo, vfrag);
  k_wprep<<<576, 256, 0, stream>>>(W1, W2, w1t, w2t);
  k_attn<<<768, 384, 0, stream>>>(xhi, xlo, vfrag, aout, o2, ml);
  hipMemsetAsync(stats, 0, 32 * sizeof(float), stream);
  k_mlp<<<1152, 128, 0, stream>>>(aout, o2, ml, w1t, w2t, b1, b2, xhi, xlo, aout, stats);
  k_ln<<<6912, 256, 0, stream>>>(aout, out, stats);
}